// Round 12
// baseline (283.844 us; speedup 1.0000x reference)
//
#include <hip/hip_runtime.h>
#include <math.h>

#define D_    256
#define H_    256
#define R_    8
#define NINIT 8192
#define LL    16
#define MM    4096
#define NTOT  (NINIT + LL*MM)   // 73728
#define TB    16                // nodes per tile
#define MP    (MM + R_*TB)      // 4224 padded slots per layer
#define NB    (MP/TB)           // 264 tiles per layer
#define KS1   16                // K-steps GEMM1 (512/32)
#define KS2   8                 // K-steps GEMM2 (256/32)
#define NT    16                // n-tiles (256/16)

#define EMB_BLKS (NINIT*64/256)        // 2048
#define PK1_BLKS (R_*KS1*NT*64/256)    // 512
#define PK2_BLKS (R_*KS2*NT*64/256)    // 256
#define PREP_BLKS (LL + EMB_BLKS + PK1_BLKS + PK2_BLKS)
#define NPART (LL*NB + EMB_BLKS)       // 6272 partial slots (6 floats each)

typedef __attribute__((ext_vector_type(8))) short short8;
typedef __attribute__((ext_vector_type(4))) float f32x4;

__device__ __forceinline__ uint bf16h(float f) {           // f32 -> bf16 bits (RNE)
    uint u = __float_as_uint(f);
    return (u + 0x7fffu + ((u >> 16) & 1u)) >> 16;
}
__device__ __forceinline__ float bf16f(uint h) { return __uint_as_float(h << 16); }

__device__ __forceinline__ void bce_terms(float val, float lab, float p, float ng,
                                          float* A, float* B, float* pOK, float* nOK,
                                          float* tp, float* tn) {
    float tot = p + ng;
    float target = p / fmaxf(tot, 1e-8f);
    float ls  = (val >= 0.f) ? -log1pf(expf(-val)) : (val  - log1pf(expf( val)));
    float lns = (val <= 0.f) ? -log1pf(expf( val)) : (-val - log1pf(expf(-val)));
    *A = lab*tot*target*ls;
    *B = lab*tot*(1.f - target)*lns;
    *pOK = (val >= 0.f) ? lab*p : 0.f;
    *nOK = (val <  0.f) ? lab*ng : 0.f;
    *tp = p*lab; *tn = ng*lab;
}

// ---------------- prep bodies ----------------
// counting sort by rule, bins padded to TB (pad slots = -1)
__device__ void sort_body(int l, int t, const int* __restrict__ rule,
                          int* __restrict__ sorted) {
    __shared__ int hist[R_], cursor[R_];
    if (t < R_) hist[t] = 0;
    __syncthreads();
    for (int m = t; m < MM; m += 256) atomicAdd(&hist[rule[l*MM + m]], 1);
    __syncthreads();
    if (t == 0) {
        int off = 0;
        for (int r = 0; r < R_; r++) { cursor[r] = off; off += ((hist[r] + TB - 1)/TB)*TB; }
    }
    for (int m = t; m < MP; m += 256) sorted[l*MP + m] = -1;
    __syncthreads();
    for (int m = t; m < MM; m += 256) {
        int r = rule[l*MM + m];
        int p = atomicAdd(&cursor[r], 1);
        sorted[l*MP + p] = m;
    }
}

// embed + fused eval for init nodes (one wave = one node; block = 4 nodes)
__device__ void embed_body(int b, int t, const float* __restrict__ itab,
                           const float* __restrict__ stab,
                           const int* __restrict__ thax, const int* __restrict__ sine,
                           float* __restrict__ store,
                           const float* __restrict__ w_eval, const float* __restrict__ b_eval,
                           const float* __restrict__ t_eval, const float* __restrict__ pt,
                           const float* __restrict__ pos, const float* __restrict__ neg,
                           const int* __restrict__ labeled, float* __restrict__ partials) {
    __shared__ float ered[4][6];
    int gid = b*256 + t;
    int n = gid >> 6, d = (gid & 63) << 2;
    int th = thax[n], si = sine[n];
    const float4 a = *(const float4*)&itab[th*D_ + d];
    const float4 bb = *(const float4*)&stab[si*D_ + d];
    float4 o; o.x = a.x+bb.x; o.y = a.y+bb.y; o.z = a.z+bb.z; o.w = a.w+bb.w;
    *(float4*)&store[(size_t)n*D_ + d] = o;
    const float4 we = *(const float4*)&w_eval[d];
    float pv = o.x*we.x + o.y*we.y + o.z*we.z + o.w*we.w;
    #pragma unroll
    for (int off = 32; off > 0; off >>= 1) pv += __shfl_xor(pv, off);
    int wvid = t >> 6;
    if ((t & 63) == 0) {
        float val = pv + b_eval[0] + pt[0]*t_eval[0];
        float A, B, pOK, nOK, tp, tn;
        bce_terms(val, (float)labeled[n], pos[n], neg[n], &A, &B, &pOK, &nOK, &tp, &tn);
        ered[wvid][0]=A; ered[wvid][1]=B; ered[wvid][2]=pOK;
        ered[wvid][3]=nOK; ered[wvid][4]=tp; ered[wvid][5]=tn;
    }
    __syncthreads();
    if (t < 6) partials[((size_t)LL*NB + b)*6 + t] =
        ered[0][t] + ered[1][t] + ered[2][t] + ered[3][t];
}

// Ph[((r*KSn + ks)*NT + nt)*64 + lane][j] = bf16(W[r][ks*32 + (lane>>4)*8 + j][nt*16 + (lane&15)])
__device__ void pack_body(int gid, const float* __restrict__ W,
                          ushort* __restrict__ Ph, int KSn) {
    int lane = gid & 63;
    int nt   = (gid >> 6) & 15;
    int ks   = (gid >> 10) % KSn;
    int r    = gid / (1024*KSn);
    int K = KSn*32;
    int k0 = ks*32 + (lane >> 4)*8;
    int c  = nt*16 + (lane & 15);
    const float* src = W + ((size_t)r*K + k0)*256 + c;
    uint h[8];
    #pragma unroll
    for (int j = 0; j < 8; j++) h[j] = bf16h(src[(size_t)j*256]);
    size_t o = (size_t)gid*8;
    *(uint4*)&Ph[o] = make_uint4(h[0]|(h[1]<<16), h[2]|(h[3]<<16), h[4]|(h[5]<<16), h[6]|(h[7]<<16));
}

__global__ __launch_bounds__(256) void prep_kernel(
        const int* __restrict__ drule, int* __restrict__ sorted,
        const float* __restrict__ itab, const float* __restrict__ stab,
        const int* __restrict__ thax, const int* __restrict__ sine,
        float* __restrict__ store,
        const float* __restrict__ W1, ushort* __restrict__ P1h,
        const float* __restrict__ W2, ushort* __restrict__ P2h,
        const float* __restrict__ w_eval, const float* __restrict__ b_eval,
        const float* __restrict__ t_eval, const float* __restrict__ pt,
        const float* __restrict__ pos, const float* __restrict__ neg,
        const int* __restrict__ labeled, float* __restrict__ partials) {
    int b = blockIdx.x, t = threadIdx.x;
    if (b < LL) {
        sort_body(b, t, drule, sorted);
    } else if (b < LL + EMB_BLKS) {
        embed_body(b - LL, t, itab, stab, thax, sine, store,
                   w_eval, b_eval, t_eval, pt, pos, neg, labeled, partials);
    } else if (b < LL + EMB_BLKS + PK1_BLKS) {
        pack_body((b - LL - EMB_BLKS)*256 + t, W1, P1h, KS1);
    } else {
        pack_body((b - LL - EMB_BLKS - PK1_BLKS)*256 + t, W2, P2h, KS2);
    }
}

// ---------------- one DAG layer + fused eval ----------------
// 264 padded 16-row tiles; 512 threads (8 waves), each wave owns TWO 16-col n-tiles:
// per k-step 2 LDS read-pairs feed 4 MFMAs + 2 B-loads. 49KB LDS + <=128 VGPR
// => 2 blocks/CU co-residency: all 264 tiles run concurrently (no straggler tail).
__global__ __launch_bounds__(512, 4) void layer_kernel(float* __restrict__ store,
        const int* __restrict__ sorted, const int* __restrict__ rule,
        const int* __restrict__ parents,
        const ushort* __restrict__ P1h, const ushort* __restrict__ P2h,
        const float* __restrict__ b1, const float* __restrict__ t1,
        const float* __restrict__ b2, const float* __restrict__ pt,
        const float* __restrict__ w_eval, const float* __restrict__ b_eval,
        const float* __restrict__ t_eval,
        const float* __restrict__ pos, const float* __restrict__ neg,
        const int* __restrict__ labeled, float* __restrict__ partials, int l) {
    __shared__ ushort Xh[TB*512], Xl[TB*512];   // 16 rows x 512 bf16 hi/lo, XOR-swizzled
    __shared__ ushort Hh[TB*256], Hl[TB*256];
    __shared__ int idx_s[TB];
    __shared__ float vred[TB][NT + 1];
    const int t = threadIdx.x, lane = t & 63, wv = t >> 6;   // wv = 0..7
    const int crow = lane & 15, kg = lane >> 4;
    const int base = l*MP + blockIdx.x*TB;
    const int idx0 = sorted[base];
    if (idx0 < 0) {                              // fully-padded tail tile
        if (t < 6) partials[((size_t)l*NB + blockIdx.x)*6 + t] = 0.f;
        return;
    }
    const int r = rule[l*MM + idx0];
    const int col0 = (2*wv)*16 + crow, col1 = (2*wv + 1)*16 + crow;
    const float tw = pt[1];
    const float bev = b_eval[0] + pt[0]*t_eval[0];
    const float bb1a = b1[r*H_ + col0] + tw * t1[r*H_ + col0];
    const float bb1b = b1[r*H_ + col1] + tw * t1[r*H_ + col1];
    const float bb2a = b2[r*D_ + col0], bb2b = b2[r*D_ + col1];
    const float we0 = w_eval[col0], we1 = w_eval[col1];

    // ---- gather: wave wv stages rows {wv, wv+8} (2 parent halves each, float4/lane) ----
    #pragma unroll
    for (int rr = 0; rr < 2; rr++) {
        int row = wv + rr*8;
        int idxr = sorted[base + row];
        if (lane == 0) idx_s[row] = idxr;
        #pragma unroll
        for (int half = 0; half < 2; half++) {
            float4 v = make_float4(0.f, 0.f, 0.f, 0.f);
            if (idxr >= 0) {
                int p = parents[(l*MM + idxr)*2 + half];
                v = *(const float4*)&store[(size_t)p*D_ + lane*4];
            }
            uint h0 = bf16h(v.x), h1 = bf16h(v.y), h2 = bf16h(v.z), h3 = bf16h(v.w);
            uint l0 = bf16h(v.x - bf16f(h0)), l1 = bf16h(v.y - bf16f(h1));
            uint l2 = bf16h(v.z - bf16f(h2)), l3 = bf16h(v.w - bf16f(h3));
            int e = half*256 + lane*4;
            int boff = (e*2) ^ ((row & 7) << 4);
            *(uint2*)&Xh[row*512 + (boff >> 1)] = make_uint2(h0|(h1<<16), h2|(h3<<16));
            *(uint2*)&Xl[row*512 + (boff >> 1)] = make_uint2(l0|(l1<<16), l2|(l3<<16));
        }
    }
    __syncthreads();

    // ---- GEMM1: [16x512] @ W1h[512x256]; wave owns n-tiles 2wv, 2wv+1 ----
    f32x4 acc0 = (f32x4){bb1a, bb1a, bb1a, bb1a};
    f32x4 acc1 = (f32x4){bb1b, bb1b, bb1b, bb1b};
    const short8* B1p = (const short8*)P1h + ((size_t)r*KS1*NT + 2*wv)*64 + lane;
    #pragma unroll
    for (int ks = 0; ks < KS1; ks++) {
        int ab = ((ks*64 + kg*16) ^ ((crow & 7) << 4)) >> 1;
        short8 xh = *(const short8*)&Xh[crow*512 + ab];
        short8 xl = *(const short8*)&Xl[crow*512 + ab];
        short8 bh0 = B1p[(size_t)ks*NT*64];
        short8 bh1 = B1p[(size_t)ks*NT*64 + 64];
        acc0 = __builtin_amdgcn_mfma_f32_16x16x32_bf16(xl, bh0, acc0, 0, 0, 0);
        acc0 = __builtin_amdgcn_mfma_f32_16x16x32_bf16(xh, bh0, acc0, 0, 0, 0);
        acc1 = __builtin_amdgcn_mfma_f32_16x16x32_bf16(xl, bh1, acc1, 0, 0, 0);
        acc1 = __builtin_amdgcn_mfma_f32_16x16x32_bf16(xh, bh1, acc1, 0, 0, 0);
    }
    // relu + split to bf16 hi/lo H (swizzled), both n-tiles
    #pragma unroll
    for (int reg = 0; reg < 4; reg++) {
        int row = kg*4 + reg;
        float ha = fmaxf(acc0[reg], 0.f), hb = fmaxf(acc1[reg], 0.f);
        uint hah = bf16h(ha), hbh = bf16h(hb);
        uint hal = bf16h(ha - bf16f(hah)), hbl = bf16h(hb - bf16f(hbh));
        int ba = (col0*2) ^ ((row & 7) << 4);
        int bb = (col1*2) ^ ((row & 7) << 4);
        Hh[row*256 + (ba >> 1)] = (ushort)hah;
        Hl[row*256 + (ba >> 1)] = (ushort)hal;
        Hh[row*256 + (bb >> 1)] = (ushort)hbh;
        Hl[row*256 + (bb >> 1)] = (ushort)hbl;
    }
    __syncthreads();

    // ---- GEMM2: [16x256] @ W2h[256x256] ----
    f32x4 acc2 = (f32x4){bb2a, bb2a, bb2a, bb2a};
    f32x4 acc3 = (f32x4){bb2b, bb2b, bb2b, bb2b};
    const short8* B2p = (const short8*)P2h + ((size_t)r*KS2*NT + 2*wv)*64 + lane;
    #pragma unroll
    for (int ks = 0; ks < KS2; ks++) {
        int ab = ((ks*64 + kg*16) ^ ((crow & 7) << 4)) >> 1;
        short8 hh = *(const short8*)&Hh[crow*256 + ab];
        short8 hl = *(const short8*)&Hl[crow*256 + ab];
        short8 bh0 = B2p[(size_t)ks*NT*64];
        short8 bh1 = B2p[(size_t)ks*NT*64 + 64];
        acc2 = __builtin_amdgcn_mfma_f32_16x16x32_bf16(hl, bh0, acc2, 0, 0, 0);
        acc2 = __builtin_amdgcn_mfma_f32_16x16x32_bf16(hh, bh0, acc2, 0, 0, 0);
        acc3 = __builtin_amdgcn_mfma_f32_16x16x32_bf16(hl, bh1, acc3, 0, 0, 0);
        acc3 = __builtin_amdgcn_mfma_f32_16x16x32_bf16(hh, bh1, acc3, 0, 0, 0);
    }
    // ---- store y (f32), both n-tiles ----
    const int ob = NINIT + l*MM;
    #pragma unroll
    for (int reg = 0; reg < 4; reg++) {
        int row = kg*4 + reg;
        int idx = idx_s[row];
        if (idx >= 0) {
            store[(size_t)(ob + idx)*D_ + col0] = acc2[reg];
            store[(size_t)(ob + idx)*D_ + col1] = acc3[reg];
        }
    }

    // ---- fused eval: val[row] = sum_col y*we (16-lane shfl + cross-wave LDS) ----
    float pv0[4], pv1[4];
    #pragma unroll
    for (int reg = 0; reg < 4; reg++) { pv0[reg] = acc2[reg]*we0; pv1[reg] = acc3[reg]*we1; }
    #pragma unroll
    for (int off = 1; off < 16; off <<= 1) {
        #pragma unroll
        for (int reg = 0; reg < 4; reg++) {
            pv0[reg] += __shfl_xor(pv0[reg], off);
            pv1[reg] += __shfl_xor(pv1[reg], off);
        }
    }
    if (crow == 0) {
        #pragma unroll
        for (int reg = 0; reg < 4; reg++) {
            int row = kg*4 + reg;
            vred[row][2*wv]     = pv0[reg];
            vred[row][2*wv + 1] = pv1[reg];
        }
    }
    __syncthreads();
    // ---- eval tail: one row per lane (t < 16) ----
    if (t < TB) {
        float val = 0.f;
        #pragma unroll
        for (int nt = 0; nt < NT; nt++) val += vred[t][nt];
        int idx = idx_s[t];
        float A=0.f, B=0.f, pOK=0.f, nOK=0.f, tp=0.f, tn=0.f;
        if (idx >= 0) {
            int n = ob + idx;
            bce_terms(val + bev, (float)labeled[n], pos[n], neg[n],
                      &A, &B, &pOK, &nOK, &tp, &tn);
        }
        #pragma unroll
        for (int off = 1; off < 16; off <<= 1) {
            A   += __shfl_xor(A, off);   B  += __shfl_xor(B, off);
            pOK += __shfl_xor(pOK, off); nOK += __shfl_xor(nOK, off);
            tp  += __shfl_xor(tp, off);  tn += __shfl_xor(tn, off);
        }
        if (t == 0) {
            float* ps = &partials[((size_t)l*NB + blockIdx.x)*6];
            ps[0]=A; ps[1]=B; ps[2]=pOK; ps[3]=nOK; ps[4]=tp; ps[5]=tn;
        }
    }
}

// ---------------- final reduce + pw + loss ----------------
__global__ __launch_bounds__(256) void final_kernel(const float* __restrict__ partials,
                                                    float* __restrict__ out) {
    int t = threadIdx.x;
    float s[6] = {0.f, 0.f, 0.f, 0.f, 0.f, 0.f};
    for (int g = t; g < NPART; g += 256) {
        #pragma unroll
        for (int j = 0; j < 6; j++) s[j] += partials[g*6 + j];
    }
    __shared__ float red[256];
    #pragma unroll
    for (int j = 0; j < 6; j++) {
        __syncthreads();
        red[t] = s[j];
        __syncthreads();
        for (int st = 128; st > 0; st >>= 1) {
            if (t < st) red[t] += red[t + st];
            __syncthreads();
        }
        s[j] = red[0];
    }
    if (t == 0) {
        float pw = s[5] / fmaxf(s[4], 1e-8f);
        out[0] = -(pw*s[0] + s[1]);
        out[1] = s[2]; out[2] = s[3]; out[3] = s[4]; out[4] = s[5];
    }
}

extern "C" void kernel_launch(void* const* d_in, const int* in_sizes, int n_in,
                              void* d_out, int out_size, void* d_ws, size_t ws_size,
                              hipStream_t stream) {
    const float* pt        = (const float*)d_in[0];
    const float* init_tab  = (const float*)d_in[1];
    const float* sine_tab  = (const float*)d_in[2];
    const float* W1        = (const float*)d_in[3];
    const float* b1        = (const float*)d_in[4];
    const float* t1        = (const float*)d_in[5];
    const float* W2        = (const float*)d_in[6];
    const float* b2        = (const float*)d_in[7];
    const float* w_eval    = (const float*)d_in[8];
    const float* b_eval    = (const float*)d_in[9];
    const float* t_eval    = (const float*)d_in[10];
    const float* pos       = (const float*)d_in[11];
    const float* neg       = (const float*)d_in[12];
    const int*   init_thax = (const int*)d_in[13];
    const int*   init_sine = (const int*)d_in[14];
    const int*   drule     = (const int*)d_in[15];
    const int*   dparents  = (const int*)d_in[16];
    const int*   labeled   = (const int*)d_in[17];
    float* out = (float*)d_out;

    // workspace layout (bytes, all 16-aligned)
    char* w = (char*)d_ws;
    const size_t STORE_B = (size_t)NTOT * D_ * 4;            // 75,497,472
    const size_t SORT_B  = (size_t)LL * MP * 4;              //    270,336
    const size_t P1_B    = (size_t)R_*KS1*NT*64*8*2;         //  2,097,152
    const size_t P2_B    = (size_t)R_*KS2*NT*64*8*2;         //  1,048,576
    float*  store    = (float*) w;                    w += STORE_B;
    int*    sorted   = (int*)   w;                    w += SORT_B;
    ushort* P1h      = (ushort*)w;                    w += P1_B;
    ushort* P2h      = (ushort*)w;                    w += P2_B;
    float*  partials = (float*) w;                    // NPART*6*4 = 150,528

    prep_kernel<<<PREP_BLKS, 256, 0, stream>>>(drule, sorted,
                                               init_tab, sine_tab,
                                               init_thax, init_sine, store,
                                               W1, P1h, W2, P2h,
                                               w_eval, b_eval, t_eval, pt,
                                               pos, neg, labeled, partials);
    for (int l = 0; l < LL; l++)
        layer_kernel<<<NB, 512, 0, stream>>>(store, sorted, drule, dparents,
                                             P1h, P2h, b1, t1, b2, pt,
                                             w_eval, b_eval, t_eval,
                                             pos, neg, labeled, partials, l);
    final_kernel<<<1, 256, 0, stream>>>(partials, out);
}

// Round 13
// 265.390 us; speedup vs baseline: 1.0695x; 1.0695x over previous
//
#include <hip/hip_runtime.h>
#include <math.h>

#define D_    256
#define H_    256
#define R_    8
#define NINIT 8192
#define LL    16
#define MM    4096
#define NTOT  (NINIT + LL*MM)   // 73728
#define TB    16                // nodes per MFMA tile/block
#define MP    (MM + R_*TB)      // 4224 padded slots per layer
#define NB    (MP/TB)           // 264 blocks per layer
#define KS1   16                // K-steps GEMM1 (512/32)
#define KS2   8                 // K-steps GEMM2 (256/32)
#define NT    16                // n-tiles (256/16)

#define EMB_BLKS (NINIT*64/256)        // 2048
#define PK1_BLKS (R_*KS1*NT*64/256)    // 512
#define PK2_BLKS (R_*KS2*NT*64/256)    // 256
#define PREP_BLKS (LL + EMB_BLKS + PK1_BLKS + PK2_BLKS)
#define NPART (LL*NB + EMB_BLKS)       // 6272 partial slots (6 floats each)

typedef __attribute__((ext_vector_type(8))) short short8;
typedef __attribute__((ext_vector_type(4))) float f32x4;

__device__ __forceinline__ uint bf16h(float f) {           // f32 -> bf16 bits (RNE)
    uint u = __float_as_uint(f);
    return (u + 0x7fffu + ((u >> 16) & 1u)) >> 16;
}
__device__ __forceinline__ float bf16f(uint h) { return __uint_as_float(h << 16); }

__device__ __forceinline__ void bce_terms(float val, float lab, float p, float ng,
                                          float* A, float* B, float* pOK, float* nOK,
                                          float* tp, float* tn) {
    float tot = p + ng;
    float target = p / fmaxf(tot, 1e-8f);
    float ls  = (val >= 0.f) ? -log1pf(expf(-val)) : (val  - log1pf(expf( val)));
    float lns = (val <= 0.f) ? -log1pf(expf( val)) : (-val - log1pf(expf(-val)));
    *A = lab*tot*target*ls;
    *B = lab*tot*(1.f - target)*lns;
    *pOK = (val >= 0.f) ? lab*p : 0.f;
    *nOK = (val <  0.f) ? lab*ng : 0.f;
    *tp = p*lab; *tn = ng*lab;
}

// ---------------- prep bodies ----------------
// counting sort by rule, bins padded to TB (pad slots = -1)
__device__ void sort_body(int l, int t, const int* __restrict__ rule,
                          int* __restrict__ sorted) {
    __shared__ int hist[R_], cursor[R_];
    if (t < R_) hist[t] = 0;
    __syncthreads();
    for (int m = t; m < MM; m += 256) atomicAdd(&hist[rule[l*MM + m]], 1);
    __syncthreads();
    if (t == 0) {
        int off = 0;
        for (int r = 0; r < R_; r++) { cursor[r] = off; off += ((hist[r] + TB - 1)/TB)*TB; }
    }
    for (int m = t; m < MP; m += 256) sorted[l*MP + m] = -1;
    __syncthreads();
    for (int m = t; m < MM; m += 256) {
        int r = rule[l*MM + m];
        int p = atomicAdd(&cursor[r], 1);
        sorted[l*MP + p] = m;
    }
}

// embed + fused eval for init nodes (one wave = one node; block = 4 nodes)
__device__ void embed_body(int b, int t, const float* __restrict__ itab,
                           const float* __restrict__ stab,
                           const int* __restrict__ thax, const int* __restrict__ sine,
                           float* __restrict__ store,
                           const float* __restrict__ w_eval, const float* __restrict__ b_eval,
                           const float* __restrict__ t_eval, const float* __restrict__ pt,
                           const float* __restrict__ pos, const float* __restrict__ neg,
                           const int* __restrict__ labeled, float* __restrict__ partials) {
    __shared__ float ered[4][6];
    int gid = b*256 + t;
    int n = gid >> 6, d = (gid & 63) << 2;
    int th = thax[n], si = sine[n];
    const float4 a = *(const float4*)&itab[th*D_ + d];
    const float4 bb = *(const float4*)&stab[si*D_ + d];
    float4 o; o.x = a.x+bb.x; o.y = a.y+bb.y; o.z = a.z+bb.z; o.w = a.w+bb.w;
    *(float4*)&store[(size_t)n*D_ + d] = o;
    const float4 we = *(const float4*)&w_eval[d];
    float pv = o.x*we.x + o.y*we.y + o.z*we.z + o.w*we.w;
    #pragma unroll
    for (int off = 32; off > 0; off >>= 1) pv += __shfl_xor(pv, off);
    int wvid = t >> 6;
    if ((t & 63) == 0) {
        float val = pv + b_eval[0] + pt[0]*t_eval[0];
        float A, B, pOK, nOK, tp, tn;
        bce_terms(val, (float)labeled[n], pos[n], neg[n], &A, &B, &pOK, &nOK, &tp, &tn);
        ered[wvid][0]=A; ered[wvid][1]=B; ered[wvid][2]=pOK;
        ered[wvid][3]=nOK; ered[wvid][4]=tp; ered[wvid][5]=tn;
    }
    __syncthreads();
    if (t < 6) partials[((size_t)LL*NB + b)*6 + t] =
        ered[0][t] + ered[1][t] + ered[2][t] + ered[3][t];
}

// Ph[((r*KSn + ks)*NT + nt)*64 + lane][j] = bf16(W[r][ks*32 + (lane>>4)*8 + j][nt*16 + (lane&15)])
__device__ void pack_body(int gid, const float* __restrict__ W,
                          ushort* __restrict__ Ph, int KSn) {
    int lane = gid & 63;
    int nt   = (gid >> 6) & 15;
    int ks   = (gid >> 10) % KSn;
    int r    = gid / (1024*KSn);
    int K = KSn*32;
    int k0 = ks*32 + (lane >> 4)*8;
    int c  = nt*16 + (lane & 15);
    const float* src = W + ((size_t)r*K + k0)*256 + c;
    uint h[8];
    #pragma unroll
    for (int j = 0; j < 8; j++) h[j] = bf16h(src[(size_t)j*256]);
    size_t o = (size_t)gid*8;
    *(uint4*)&Ph[o] = make_uint4(h[0]|(h[1]<<16), h[2]|(h[3]<<16), h[4]|(h[5]<<16), h[6]|(h[7]<<16));
}

__global__ __launch_bounds__(256) void prep_kernel(
        const int* __restrict__ drule, int* __restrict__ sorted,
        const float* __restrict__ itab, const float* __restrict__ stab,
        const int* __restrict__ thax, const int* __restrict__ sine,
        float* __restrict__ store,
        const float* __restrict__ W1, ushort* __restrict__ P1h,
        const float* __restrict__ W2, ushort* __restrict__ P2h,
        const float* __restrict__ w_eval, const float* __restrict__ b_eval,
        const float* __restrict__ t_eval, const float* __restrict__ pt,
        const float* __restrict__ pos, const float* __restrict__ neg,
        const int* __restrict__ labeled, float* __restrict__ partials) {
    int b = blockIdx.x, t = threadIdx.x;
    if (b < LL) {
        sort_body(b, t, drule, sorted);
    } else if (b < LL + EMB_BLKS) {
        embed_body(b - LL, t, itab, stab, thax, sine, store,
                   w_eval, b_eval, t_eval, pt, pos, neg, labeled, partials);
    } else if (b < LL + EMB_BLKS + PK1_BLKS) {
        pack_body((b - LL - EMB_BLKS)*256 + t, W1, P1h, KS1);
    } else {
        pack_body((b - LL - EMB_BLKS - PK1_BLKS)*256 + t, W2, P2h, KS2);
    }
}

// ---------------- one DAG layer + fused eval ----------------
// EXACT round-5/6 GEMM body (the 238us config): 264 padded 16-row tiles, 1024 thr,
// 16 waves, 1 n-tile/wave, hi-only weights, split-bf16 activations, inline B-loads.
// Only addition: fused eval/loss epilogue (reads acc2 from registers; no store re-read).
__global__ __launch_bounds__(1024) void layer_kernel(float* __restrict__ store,
        const int* __restrict__ sorted, const int* __restrict__ rule,
        const int* __restrict__ parents,
        const ushort* __restrict__ P1h, const ushort* __restrict__ P2h,
        const float* __restrict__ b1, const float* __restrict__ t1,
        const float* __restrict__ b2, const float* __restrict__ pt,
        const float* __restrict__ w_eval, const float* __restrict__ b_eval,
        const float* __restrict__ t_eval,
        const float* __restrict__ pos, const float* __restrict__ neg,
        const int* __restrict__ labeled, float* __restrict__ partials, int l) {
    __shared__ ushort Xh[TB*512], Xl[TB*512];   // 16 rows x 512 bf16 hi/lo, swizzled
    __shared__ ushort Hh[TB*256], Hl[TB*256];
    __shared__ int idx_s[TB];
    __shared__ float vred[TB][17];
    const int t = threadIdx.x, lane = t & 63, wv = t >> 6;   // wv = 0..15
    if (t < TB) idx_s[t] = sorted[l*MP + blockIdx.x*TB + t];
    __syncthreads();
    if (idx_s[0] < 0) {                          // fully-padded tail tile
        if (t < 6) partials[((size_t)l*NB + blockIdx.x)*6 + t] = 0.f;
        return;
    }
    const int r = rule[l*MM + idx_s[0]];
    const float tw = pt[1];

    // ---- stage X: wave wv stages row wv (one parent half per iter, float4/lane) ----
    {
        const int row = wv;
        const int idx = idx_s[row];
        #pragma unroll
        for (int half = 0; half < 2; half++) {
            float4 v = make_float4(0.f, 0.f, 0.f, 0.f);
            if (idx >= 0) {
                int p = parents[(l*MM + idx)*2 + half];
                v = *(const float4*)&store[(size_t)p*D_ + lane*4];
            }
            uint h0 = bf16h(v.x), h1 = bf16h(v.y), h2 = bf16h(v.z), h3 = bf16h(v.w);
            uint l0 = bf16h(v.x - bf16f(h0)), l1 = bf16h(v.y - bf16f(h1));
            uint l2 = bf16h(v.z - bf16f(h2)), l3 = bf16h(v.w - bf16f(h3));
            int e = half*256 + lane*4;
            int boff = (e*2) ^ ((row & 7) << 4);
            *(uint2*)&Xh[row*512 + (boff >> 1)] = make_uint2(h0|(h1<<16), h2|(h3<<16));
            *(uint2*)&Xl[row*512 + (boff >> 1)] = make_uint2(l0|(l1<<16), l2|(l3<<16));
        }
    }
    __syncthreads();

    const int crow = lane & 15, kg = lane >> 4;
    const int col = wv*16 + crow;
    const float bev = b_eval[0] + pt[0]*t_eval[0];
    const float we  = w_eval[col];

    // ---- GEMM1: [16x512] @ W1h[512x256], 2-pass (xl,xh); wave owns n-tile wv ----
    f32x4 acc;
    { float bb = b1[r*H_ + col] + tw * t1[r*H_ + col]; acc = (f32x4){bb, bb, bb, bb}; }
    const short8* B1hp = (const short8*)P1h + ((size_t)r*KS1*NT + wv)*64 + lane;
    #pragma unroll
    for (int ks = 0; ks < KS1; ks++) {
        int ab = ((ks*64 + kg*16) ^ ((crow & 7) << 4)) >> 1;
        short8 xh = *(const short8*)&Xh[crow*512 + ab];
        short8 xl = *(const short8*)&Xl[crow*512 + ab];
        short8 bh = B1hp[(size_t)ks*NT*64];
        acc = __builtin_amdgcn_mfma_f32_16x16x32_bf16(xl, bh, acc, 0, 0, 0);
        acc = __builtin_amdgcn_mfma_f32_16x16x32_bf16(xh, bh, acc, 0, 0, 0);
    }
    // relu + split to bf16 hi/lo H (swizzled)
    #pragma unroll
    for (int reg = 0; reg < 4; reg++) {
        int row = kg*4 + reg;
        float h = fmaxf(acc[reg], 0.f);
        uint hh = bf16h(h);
        uint hl = bf16h(h - bf16f(hh));
        int boff = (col*2) ^ ((row & 7) << 4);
        Hh[row*256 + (boff >> 1)] = (ushort)hh;
        Hl[row*256 + (boff >> 1)] = (ushort)hl;
    }
    __syncthreads();

    // ---- GEMM2: [16x256] @ W2h[256x256], 2-pass (hl,hh); wave owns n-tile wv ----
    f32x4 acc2;
    { float bb = b2[r*D_ + col]; acc2 = (f32x4){bb, bb, bb, bb}; }
    const short8* B2hp = (const short8*)P2h + ((size_t)r*KS2*NT + wv)*64 + lane;
    #pragma unroll
    for (int ks = 0; ks < KS2; ks++) {
        int ab = ((ks*64 + kg*16) ^ ((crow & 7) << 4)) >> 1;
        short8 hh = *(const short8*)&Hh[crow*256 + ab];
        short8 hl = *(const short8*)&Hl[crow*256 + ab];
        short8 bh = B2hp[(size_t)ks*NT*64];
        acc2 = __builtin_amdgcn_mfma_f32_16x16x32_bf16(hl, bh, acc2, 0, 0, 0);
        acc2 = __builtin_amdgcn_mfma_f32_16x16x32_bf16(hh, bh, acc2, 0, 0, 0);
    }
    // ---- store y (f32) ----
    const int ob = NINIT + l*MM;
    #pragma unroll
    for (int reg = 0; reg < 4; reg++) {
        int row = kg*4 + reg;
        int idx = idx_s[row];
        if (idx >= 0) store[(size_t)(ob + idx)*D_ + col] = acc2[reg];
    }

    // ---- fused eval: val[row] = sum_col y*we (16-lane shfl + cross-wave LDS) ----
    float pv[4];
    #pragma unroll
    for (int reg = 0; reg < 4; reg++) pv[reg] = acc2[reg] * we;
    #pragma unroll
    for (int off = 1; off < 16; off <<= 1) {
        #pragma unroll
        for (int reg = 0; reg < 4; reg++) pv[reg] += __shfl_xor(pv[reg], off);
    }
    if (crow == 0) {
        #pragma unroll
        for (int reg = 0; reg < 4; reg++) vred[kg*4 + reg][wv] = pv[reg];
    }
    __syncthreads();
    if (t < TB) {                                // wave 0, lanes 0..15: one row each
        float val = 0.f;
        #pragma unroll
        for (int w16 = 0; w16 < 16; w16++) val += vred[t][w16];
        int idx = idx_s[t];
        float A=0.f, B=0.f, pOK=0.f, nOK=0.f, tp=0.f, tn=0.f;
        if (idx >= 0) {
            int n = ob + idx;
            bce_terms(val + bev, (float)labeled[n], pos[n], neg[n],
                      &A, &B, &pOK, &nOK, &tp, &tn);
        }
        #pragma unroll
        for (int off = 1; off < 16; off <<= 1) {
            A   += __shfl_xor(A, off);   B  += __shfl_xor(B, off);
            pOK += __shfl_xor(pOK, off); nOK += __shfl_xor(nOK, off);
            tp  += __shfl_xor(tp, off);  tn += __shfl_xor(tn, off);
        }
        if (t == 0) {
            float* ps = &partials[((size_t)l*NB + blockIdx.x)*6];
            ps[0]=A; ps[1]=B; ps[2]=pOK; ps[3]=nOK; ps[4]=tp; ps[5]=tn;
        }
    }
}

// ---------------- final reduce + pw + loss ----------------
__global__ __launch_bounds__(256) void final_kernel(const float* __restrict__ partials,
                                                    float* __restrict__ out) {
    int t = threadIdx.x;
    float s[6] = {0.f, 0.f, 0.f, 0.f, 0.f, 0.f};
    for (int g = t; g < NPART; g += 256) {
        #pragma unroll
        for (int j = 0; j < 6; j++) s[j] += partials[g*6 + j];
    }
    __shared__ float red[256];
    #pragma unroll
    for (int j = 0; j < 6; j++) {
        __syncthreads();
        red[t] = s[j];
        __syncthreads();
        for (int st = 128; st > 0; st >>= 1) {
            if (t < st) red[t] += red[t + st];
            __syncthreads();
        }
        s[j] = red[0];
    }
    if (t == 0) {
        float pw = s[5] / fmaxf(s[4], 1e-8f);
        out[0] = -(pw*s[0] + s[1]);
        out[1] = s[2]; out[2] = s[3]; out[3] = s[4]; out[4] = s[5];
    }
}

extern "C" void kernel_launch(void* const* d_in, const int* in_sizes, int n_in,
                              void* d_out, int out_size, void* d_ws, size_t ws_size,
                              hipStream_t stream) {
    const float* pt        = (const float*)d_in[0];
    const float* init_tab  = (const float*)d_in[1];
    const float* sine_tab  = (const float*)d_in[2];
    const float* W1        = (const float*)d_in[3];
    const float* b1        = (const float*)d_in[4];
    const float* t1        = (const float*)d_in[5];
    const float* W2        = (const float*)d_in[6];
    const float* b2        = (const float*)d_in[7];
    const float* w_eval    = (const float*)d_in[8];
    const float* b_eval    = (const float*)d_in[9];
    const float* t_eval    = (const float*)d_in[10];
    const float* pos       = (const float*)d_in[11];
    const float* neg       = (const float*)d_in[12];
    const int*   init_thax = (const int*)d_in[13];
    const int*   init_sine = (const int*)d_in[14];
    const int*   drule     = (const int*)d_in[15];
    const int*   dparents  = (const int*)d_in[16];
    const int*   labeled   = (const int*)d_in[17];
    float* out = (float*)d_out;

    // workspace layout (bytes, all 16-aligned)
    char* w = (char*)d_ws;
    const size_t STORE_B = (size_t)NTOT * D_ * 4;            // 75,497,472
    const size_t SORT_B  = (size_t)LL * MP * 4;              //    270,336
    const size_t P1_B    = (size_t)R_*KS1*NT*64*8*2;         //  2,097,152
    const size_t P2_B    = (size_t)R_*KS2*NT*64*8*2;         //  1,048,576
    float*  store    = (float*) w;                    w += STORE_B;
    int*    sorted   = (int*)   w;                    w += SORT_B;
    ushort* P1h      = (ushort*)w;                    w += P1_B;
    ushort* P2h      = (ushort*)w;                    w += P2_B;
    float*  partials = (float*) w;                    // NPART*6*4 = 150,528

    prep_kernel<<<PREP_BLKS, 256, 0, stream>>>(drule, sorted,
                                               init_tab, sine_tab,
                                               init_thax, init_sine, store,
                                               W1, P1h, W2, P2h,
                                               w_eval, b_eval, t_eval, pt,
                                               pos, neg, labeled, partials);
    for (int l = 0; l < LL; l++)
        layer_kernel<<<NB, 1024, 0, stream>>>(store, sorted, drule, dparents,
                                              P1h, P2h, b1, t1, b2, pt,
                                              w_eval, b_eval, t_eval,
                                              pos, neg, labeled, partials, l);
    final_kernel<<<1, 256, 0, stream>>>(partials, out);
}

// Round 14
// 263.331 us; speedup vs baseline: 1.0779x; 1.0078x over previous
//
#include <hip/hip_runtime.h>
#include <math.h>

#define D_    256
#define H_    256
#define R_    8
#define NINIT 8192
#define LL    16
#define MM    4096
#define NTOT  (NINIT + LL*MM)   // 73728
#define TB    16                // nodes per tile
#define NTILE (MM/TB)           // 256 tight-packed tiles per layer (1 block/CU)
#define KS1   16                // K-steps GEMM1 (512/32)
#define KS2   8                 // K-steps GEMM2 (256/32)
#define NT    16                // n-tiles (256/16)
#define EVB   16                // nodes per eval block
#define GE    (NTOT/EVB)        // 4608

#define EMB_BLKS (NINIT*64/256)        // 2048
#define PK1_BLKS (R_*KS1*NT*64/256)    // 512
#define PK2_BLKS (R_*KS2*NT*64/256)    // 256
#define PREP_BLKS (LL + EMB_BLKS + PK1_BLKS + PK2_BLKS)

typedef __attribute__((ext_vector_type(8))) short short8;
typedef __attribute__((ext_vector_type(4))) float f32x4;

__device__ __forceinline__ uint bf16h(float f) {           // f32 -> bf16 bits (RNE)
    uint u = __float_as_uint(f);
    return (u + 0x7fffu + ((u >> 16) & 1u)) >> 16;
}
__device__ __forceinline__ float bf16f(uint h) { return __uint_as_float(h << 16); }

// ---------------- prep bodies ----------------
// tight counting sort by rule (no padding) + exact prefix sums
__device__ void sort_body(int l, int t, const int* __restrict__ rule,
                          int* __restrict__ sorted, int* __restrict__ prefix) {
    __shared__ int hist[R_], cursor[R_], pre[R_+1];
    if (t < R_) hist[t] = 0;
    __syncthreads();
    for (int m = t; m < MM; m += 256) atomicAdd(&hist[rule[l*MM + m]], 1);
    __syncthreads();
    if (t == 0) {
        pre[0] = 0;
        for (int r = 0; r < R_; r++) { pre[r+1] = pre[r] + hist[r]; cursor[r] = pre[r]; }
    }
    __syncthreads();
    if (t < R_+1) prefix[l*(R_+1) + t] = pre[t];
    for (int m = t; m < MM; m += 256) {
        int r = rule[l*MM + m];
        int p = atomicAdd(&cursor[r], 1);
        sorted[l*MM + p] = m;
    }
}

__device__ void embed_body(int gid, const float* __restrict__ itab,
                           const float* __restrict__ stab,
                           const int* __restrict__ thax, const int* __restrict__ sine,
                           float* __restrict__ store) {
    int n = gid >> 6, d = (gid & 63) << 2;
    int th = thax[n], si = sine[n];
    const float4 a = *(const float4*)&itab[th*D_ + d];
    const float4 b = *(const float4*)&stab[si*D_ + d];
    float4 o; o.x = a.x+b.x; o.y = a.y+b.y; o.z = a.z+b.z; o.w = a.w+b.w;
    *(float4*)&store[(size_t)n*D_ + d] = o;
}

// Ph[((r*KSn + ks)*NT + nt)*64 + lane][j] = bf16(W[r][ks*32 + (lane>>4)*8 + j][nt*16 + (lane&15)])
__device__ void pack_body(int gid, const float* __restrict__ W,
                          ushort* __restrict__ Ph, int KSn) {
    int lane = gid & 63;
    int nt   = (gid >> 6) & 15;
    int ks   = (gid >> 10) % KSn;
    int r    = gid / (1024*KSn);
    int K = KSn*32;
    int k0 = ks*32 + (lane >> 4)*8;
    int c  = nt*16 + (lane & 15);
    const float* src = W + ((size_t)r*K + k0)*256 + c;
    uint h[8];
    #pragma unroll
    for (int j = 0; j < 8; j++) h[j] = bf16h(src[(size_t)j*256]);
    size_t o = (size_t)gid*8;
    *(uint4*)&Ph[o] = make_uint4(h[0]|(h[1]<<16), h[2]|(h[3]<<16), h[4]|(h[5]<<16), h[6]|(h[7]<<16));
}

__global__ __launch_bounds__(256) void prep_kernel(
        const int* __restrict__ drule, int* __restrict__ sorted, int* __restrict__ prefix,
        const float* __restrict__ itab, const float* __restrict__ stab,
        const int* __restrict__ thax, const int* __restrict__ sine,
        float* __restrict__ store,
        const float* __restrict__ W1, ushort* __restrict__ P1h,
        const float* __restrict__ W2, ushort* __restrict__ P2h) {
    int b = blockIdx.x, t = threadIdx.x;
    if (b < LL) {
        sort_body(b, t, drule, sorted, prefix);
    } else if (b < LL + EMB_BLKS) {
        embed_body((b - LL)*256 + t, itab, stab, thax, sine, store);
    } else if (b < LL + EMB_BLKS + PK1_BLKS) {
        pack_body((b - LL - EMB_BLKS)*256 + t, W1, P1h, KS1);
    } else {
        pack_body((b - LL - EMB_BLKS - PK1_BLKS)*256 + t, W2, P2h, KS2);
    }
}

// ---------------- one DAG layer ----------------
// EXACT round-6 GEMM body; only the tiling changed: 256 tight-packed tiles
// (grid = 256 = 1 block/CU, no serial tail). Straddle tiles (rule boundary
// inside tile, <=7/layer) run one GEMM pass per overlapping rule; X staged once.
__global__ __launch_bounds__(1024) void layer_kernel(float* __restrict__ store,
        const int* __restrict__ sorted, const int* __restrict__ prefix,
        const int* __restrict__ parents,
        const ushort* __restrict__ P1h, const ushort* __restrict__ P2h,
        const float* __restrict__ b1, const float* __restrict__ t1,
        const float* __restrict__ b2, const float* __restrict__ pt, int l) {
    __shared__ ushort Xh[TB*512], Xl[TB*512];   // 16 rows x 512 bf16 hi/lo, swizzled
    __shared__ ushort Hh[TB*256], Hl[TB*256];
    __shared__ int idx_s[TB];
    __shared__ int pre_s[R_+1];
    const int t = threadIdx.x, lane = t & 63, wv = t >> 6;   // wv = 0..15
    if (t < R_+1) pre_s[t] = prefix[l*(R_+1) + t];
    const float tw = pt[1];

    // ---- stage X: wave wv stages row wv (one parent half per iter, float4/lane) ----
    const int m = sorted[l*MM + blockIdx.x*TB + wv];
    if (lane == 0) idx_s[wv] = m;
    #pragma unroll
    for (int half = 0; half < 2; half++) {
        int p = parents[(l*MM + m)*2 + half];
        float4 v = *(const float4*)&store[(size_t)p*D_ + lane*4];
        uint h0 = bf16h(v.x), h1 = bf16h(v.y), h2 = bf16h(v.z), h3 = bf16h(v.w);
        uint l0 = bf16h(v.x - bf16f(h0)), l1 = bf16h(v.y - bf16f(h1));
        uint l2 = bf16h(v.z - bf16f(h2)), l3 = bf16h(v.w - bf16f(h3));
        int e = half*256 + lane*4;
        int boff = (e*2) ^ ((wv & 7) << 4);
        *(uint2*)&Xh[wv*512 + (boff >> 1)] = make_uint2(h0|(h1<<16), h2|(h3<<16));
        *(uint2*)&Xl[wv*512 + (boff >> 1)] = make_uint2(l0|(l1<<16), l2|(l3<<16));
    }
    __syncthreads();

    const int crow = lane & 15, kg = lane >> 4;
    const int col = wv*16 + crow;
    const int row0 = blockIdx.x*TB;
    const int ob = NINIT + l*MM;

    // ---- rule passes: uniform tiles run once; straddle tiles once per rule ----
    for (int r = 0; r < R_; r++) {
        int lo = (row0 > pre_s[r] ? row0 : pre_s[r]) - row0;
        int hi = (row0+TB < pre_s[r+1] ? row0+TB : pre_s[r+1]) - row0;
        if (lo >= hi) continue;

        // GEMM1: [16x512] @ W1h[512x256], 2-pass (xl, xh); wave owns n-tile wv
        f32x4 acc;
        { float bb = b1[r*H_ + col] + tw * t1[r*H_ + col]; acc = (f32x4){bb, bb, bb, bb}; }
        const short8* B1hp = (const short8*)P1h + ((size_t)r*KS1*NT + wv)*64 + lane;
        #pragma unroll
        for (int ks = 0; ks < KS1; ks++) {
            int ab = ((ks*64 + kg*16) ^ ((crow & 7) << 4)) >> 1;
            short8 xh = *(const short8*)&Xh[crow*512 + ab];
            short8 xl = *(const short8*)&Xl[crow*512 + ab];
            short8 bh = B1hp[(size_t)ks*NT*64];
            acc = __builtin_amdgcn_mfma_f32_16x16x32_bf16(xl, bh, acc, 0, 0, 0);
            acc = __builtin_amdgcn_mfma_f32_16x16x32_bf16(xh, bh, acc, 0, 0, 0);
        }
        __syncthreads();                      // previous pass done reading H
        // relu + split to bf16 hi/lo H (swizzled)
        #pragma unroll
        for (int reg = 0; reg < 4; reg++) {
            int row = kg*4 + reg;
            float h = fmaxf(acc[reg], 0.f);
            uint hh = bf16h(h);
            uint hl = bf16h(h - bf16f(hh));
            int boff = (col*2) ^ ((row & 7) << 4);
            Hh[row*256 + (boff >> 1)] = (ushort)hh;
            Hl[row*256 + (boff >> 1)] = (ushort)hl;
        }
        __syncthreads();

        // GEMM2: [16x256] @ W2h[256x256], 2-pass (hl, hh)
        f32x4 acc2;
        { float bb = b2[r*D_ + col]; acc2 = (f32x4){bb, bb, bb, bb}; }
        const short8* B2hp = (const short8*)P2h + ((size_t)r*KS2*NT + wv)*64 + lane;
        #pragma unroll
        for (int ks = 0; ks < KS2; ks++) {
            int ab = ((ks*64 + kg*16) ^ ((crow & 7) << 4)) >> 1;
            short8 hh = *(const short8*)&Hh[crow*256 + ab];
            short8 hl = *(const short8*)&Hl[crow*256 + ab];
            short8 bh = B2hp[(size_t)ks*NT*64];
            acc2 = __builtin_amdgcn_mfma_f32_16x16x32_bf16(hl, bh, acc2, 0, 0, 0);
            acc2 = __builtin_amdgcn_mfma_f32_16x16x32_bf16(hh, bh, acc2, 0, 0, 0);
        }
        // store y (f32) for rows owned by rule r
        #pragma unroll
        for (int reg = 0; reg < 4; reg++) {
            int row = kg*4 + reg;
            if (row >= lo && row < hi)
                store[(size_t)(ob + idx_s[row])*D_ + col] = acc2[reg];
        }
    }
}

// ---------------- eval_net + loss partials (A, B, posOK, negOK, tot_pos, tot_neg) ----------------
__global__ __launch_bounds__(256) void eval_kernel(const float* __restrict__ store,
        const float* __restrict__ w_eval, const float* __restrict__ b_eval,
        const float* __restrict__ t_eval, const float* __restrict__ pt,
        const float* __restrict__ pos, const float* __restrict__ neg,
        const int* __restrict__ labeled, float* __restrict__ partials) {
    int t = threadIdx.x, lane = t & 63, wv = t >> 6;
    const float4 w4 = *(const float4*)&w_eval[lane*4];
    const float bev = b_eval[0] + pt[0]*t_eval[0];
    float A = 0.f, B = 0.f, pOK = 0.f, nOK = 0.f, tp = 0.f, tn = 0.f;
    int n0 = blockIdx.x * EVB;
    #pragma unroll
    for (int k = 0; k < 4; k++) {
        int n = n0 + wv*4 + k;
        const float4 s = *(const float4*)&store[(size_t)n*D_ + lane*4];
        float d = s.x*w4.x + s.y*w4.y + s.z*w4.z + s.w*w4.w;
        #pragma unroll
        for (int off = 32; off > 0; off >>= 1) d += __shfl_xor(d, off);
        if (lane == 0) {
            float val = d + bev;
            float lab = (float)labeled[n];
            float p = pos[n], ng = neg[n];
            float tot = p + ng;
            float target = p / fmaxf(tot, 1e-8f);
            float ls  = (val >= 0.f) ? -log1pf(expf(-val)) : (val  - log1pf(expf( val)));
            float lns = (val <= 0.f) ? -log1pf(expf( val)) : (-val - log1pf(expf(-val)));
            A += lab*tot*target*ls;
            B += lab*tot*(1.f - target)*lns;
            if (val >= 0.f) pOK += lab*p; else nOK += lab*ng;
            tp += p*lab; tn += ng*lab;
        }
    }
    __shared__ float red[4][6];
    if (lane == 0) {
        red[wv][0] = A;  red[wv][1] = B;  red[wv][2] = pOK;
        red[wv][3] = nOK; red[wv][4] = tp; red[wv][5] = tn;
    }
    __syncthreads();
    if (t < 6) partials[blockIdx.x*6 + t] = red[0][t] + red[1][t] + red[2][t] + red[3][t];
}

// ---------------- final reduce + pw + loss ----------------
__global__ __launch_bounds__(256) void final_kernel(const float* __restrict__ partials,
                                                    float* __restrict__ out) {
    int t = threadIdx.x;
    float s[6] = {0.f, 0.f, 0.f, 0.f, 0.f, 0.f};
    for (int g = t; g < GE; g += 256) {
        #pragma unroll
        for (int j = 0; j < 6; j++) s[j] += partials[g*6 + j];
    }
    __shared__ float red[256];
    #pragma unroll
    for (int j = 0; j < 6; j++) {
        __syncthreads();
        red[t] = s[j];
        __syncthreads();
        for (int st = 128; st > 0; st >>= 1) {
            if (t < st) red[t] += red[t + st];
            __syncthreads();
        }
        s[j] = red[0];
    }
    if (t == 0) {
        float pw = s[5] / fmaxf(s[4], 1e-8f);
        out[0] = -(pw*s[0] + s[1]);
        out[1] = s[2]; out[2] = s[3]; out[3] = s[4]; out[4] = s[5];
    }
}

extern "C" void kernel_launch(void* const* d_in, const int* in_sizes, int n_in,
                              void* d_out, int out_size, void* d_ws, size_t ws_size,
                              hipStream_t stream) {
    const float* pt        = (const float*)d_in[0];
    const float* init_tab  = (const float*)d_in[1];
    const float* sine_tab  = (const float*)d_in[2];
    const float* W1        = (const float*)d_in[3];
    const float* b1        = (const float*)d_in[4];
    const float* t1        = (const float*)d_in[5];
    const float* W2        = (const float*)d_in[6];
    const float* b2        = (const float*)d_in[7];
    const float* w_eval    = (const float*)d_in[8];
    const float* b_eval    = (const float*)d_in[9];
    const float* t_eval    = (const float*)d_in[10];
    const float* pos       = (const float*)d_in[11];
    const float* neg       = (const float*)d_in[12];
    const int*   init_thax = (const int*)d_in[13];
    const int*   init_sine = (const int*)d_in[14];
    const int*   drule     = (const int*)d_in[15];
    const int*   dparents  = (const int*)d_in[16];
    const int*   labeled   = (const int*)d_in[17];
    float* out = (float*)d_out;

    // workspace layout (bytes, all 16-aligned)
    char* w = (char*)d_ws;
    const size_t STORE_B = (size_t)NTOT * D_ * 4;            // 75,497,472
    const size_t SORT_B  = (size_t)LL * MM * 4;              //    262,144
    const size_t PREF_B  = 1024;                             // LL*9*4 padded
    const size_t P1_B    = (size_t)R_*KS1*NT*64*8*2;         //  2,097,152
    const size_t P2_B    = (size_t)R_*KS2*NT*64*8*2;         //  1,048,576
    float*  store    = (float*) w;                    w += STORE_B;
    int*    sorted   = (int*)   w;                    w += SORT_B;
    int*    prefix   = (int*)   w;                    w += PREF_B;
    ushort* P1h      = (ushort*)w;                    w += P1_B;
    ushort* P2h      = (ushort*)w;                    w += P2_B;
    float*  partials = (float*) w;                    // GE*6*4 = 110,592

    prep_kernel<<<PREP_BLKS, 256, 0, stream>>>(drule, sorted, prefix,
                                               init_tab, sine_tab,
                                               init_thax, init_sine, store,
                                               W1, P1h, W2, P2h);
    for (int l = 0; l < LL; l++)
        layer_kernel<<<NTILE, 1024, 0, stream>>>(store, sorted, prefix, dparents,
                                                 P1h, P2h, b1, t1, b2, pt, l);
    eval_kernel <<<GE, 256, 0, stream>>>(store, w_eval, b_eval, t_eval, pt,
                                         pos, neg, labeled, partials);
    final_kernel<<<1, 256, 0, stream>>>(partials, out);
}